// Round 1
// baseline (323.370 us; speedup 1.0000x reference)
//
#include <hip/hip_runtime.h>
#include <hip/hip_bf16.h>

#define BB 2
#define SS 2048
#define EE 1024
#define HH 16
#define DD 64
#define MT (BB*SS)     // 4096 tokens
#define NQ (3*EE)      // 3072

typedef unsigned short u16;
typedef __bf16 bf16t;
typedef bf16t bf16x8 __attribute__((ext_vector_type(8)));
typedef short short8v __attribute__((ext_vector_type(8)));
typedef float f32x4 __attribute__((ext_vector_type(4)));

#define AS1 __attribute__((address_space(1)))
#define AS3 __attribute__((address_space(3)))

__device__ __forceinline__ u16 f2b(float f) {
  unsigned u = __builtin_bit_cast(unsigned, f);
  u += 0x7FFF + ((u >> 16) & 1);   // RNE
  return (u16)(u >> 16);
}

__device__ __forceinline__ void gload_lds16(const u16* g, u16* l) {
  __builtin_amdgcn_global_load_lds((AS1 void*)(g), (AS3 void*)(l), 16, 0, 0);
}

__device__ __forceinline__ f32x4 mfma_bf16(short8v a, short8v b, f32x4 c) {
  return __builtin_amdgcn_mfma_f32_16x16x32_bf16(
      __builtin_bit_cast(bf16x8, a), __builtin_bit_cast(bf16x8, b), c, 0, 0, 0);
}

// ---------------- prologue: casts / transposes ----------------
__global__ void __launch_bounds__(256) cast_kernel(const float* __restrict__ in,
                                                   u16* __restrict__ out, int n) {
  int i = (blockIdx.x * 256 + threadIdx.x) * 4;
  if (i + 3 < n) {
    float4 v = *(const float4*)(in + i);
    ushort4 o;
    o.x = f2b(v.x); o.y = f2b(v.y); o.z = f2b(v.z); o.w = f2b(v.w);
    *(ushort4*)(out + i) = o;
  }
}

// W [K][N] f32 -> WT [N][K] bf16
__global__ void __launch_bounds__(256) transpose_kernel(const float* __restrict__ W,
                                                        u16* __restrict__ WT,
                                                        int K, int N) {
  int n = blockIdx.x;
  int k = blockIdx.y * 256 + threadIdx.x;
  WT[(size_t)n * K + k] = f2b(W[(size_t)k * N + n]);
}

// ---------------- QKV GEMM: C[4096,3072] = x @ Wqkv + b, scatter to Q,K,Vt ----------------
__global__ void __launch_bounds__(256) gemm_qkv_kernel(
    const u16* __restrict__ A, const u16* __restrict__ BT,
    const float* __restrict__ bias,
    u16* __restrict__ Qs, u16* __restrict__ Ks, u16* __restrict__ Vt) {
  __shared__ u16 As[4096];
  __shared__ u16 Bs[4096];
  const int K = EE;
  int tid = threadIdx.x;
  int w = tid >> 6, lane = tid & 63;
  int g = lane >> 4, q = lane & 15;
  int m0 = blockIdx.y * 128, n0 = blockIdx.x * 128;
  int wm = (w >> 1) * 64, wn = (w & 1) * 64;

  f32x4 acc[4][4] = {};

  int r = tid >> 2;
  int kc = (tid & 3) * 8;
  const u16* ga = A + (size_t)(m0 + r) * K + kc;
  const u16* gb = BT + (size_t)(n0 + r) * K + kc;
  u16* lA0 = As + w * 512;
  u16* lA1 = As + 2048 + w * 512;
  u16* lB0 = Bs + w * 512;
  u16* lB1 = Bs + 2048 + w * 512;

  for (int k0 = 0; k0 < K; k0 += 32) {
    gload_lds16(ga, lA0);
    gload_lds16(ga + 64 * K, lA1);
    gload_lds16(gb, lB0);
    gload_lds16(gb + 64 * K, lB1);
    ga += 32; gb += 32;
    __syncthreads();
    short8v af[4], bfv[4];
#pragma unroll
    for (int m = 0; m < 4; ++m)
      af[m] = *(const short8v*)(As + (wm + m * 16 + q) * 32 + g * 8);
#pragma unroll
    for (int n = 0; n < 4; ++n)
      bfv[n] = *(const short8v*)(Bs + (wn + n * 16 + q) * 32 + g * 8);
#pragma unroll
    for (int m = 0; m < 4; ++m)
#pragma unroll
      for (int n = 0; n < 4; ++n)
        acc[m][n] = mfma_bf16(af[m], bfv[n], acc[m][n]);
    __syncthreads();
  }

#pragma unroll
  for (int m = 0; m < 4; ++m) {
    int row0 = m0 + wm + m * 16 + g * 4;
#pragma unroll
    for (int n = 0; n < 4; ++n) {
      int col = n0 + wn + n * 16 + q;
      float bi = bias[col];
      int t = col >> 10;
      int h = (col >> 6) & 15;
      int d = col & 63;
#pragma unroll
      for (int r2 = 0; r2 < 4; ++r2) {
        int row = row0 + r2;
        int b = row >> 11, s = row & 2047;
        float v = acc[m][n][r2] + bi;
        size_t bh = (size_t)b * HH + h;
        if (t == 0)      Qs[(bh * SS + s) * DD + d] = f2b(v * 0.125f);
        else if (t == 1) Ks[(bh * SS + s) * DD + d] = f2b(v);
        else             Vt[(bh * DD + d) * SS + s] = f2b(v);
      }
    }
  }
}

// ---------------- causal flash attention ----------------
__global__ void __launch_bounds__(256) attn_kernel(
    const u16* __restrict__ Qg, const u16* __restrict__ Kg,
    const u16* __restrict__ Vg, u16* __restrict__ O) {
  __shared__ u16 Plds[4 * 16 * 64];   // per-wave 16x64 bf16, XOR-swizzled
  int tid = threadIdx.x;
  int w = tid >> 6, lane = tid & 63;
  int g = lane >> 4, q = lane & 15;
  int bh = blockIdx.y;
  int qt = blockIdx.x;
  int qrow0 = qt * 64 + w * 16;
  const u16* Qp = Qg + (size_t)bh * SS * DD;
  const u16* Kp = Kg + (size_t)bh * SS * DD;
  const u16* Vp = Vg + (size_t)bh * DD * SS;

  short8v aq[2];
#pragma unroll
  for (int j = 0; j < 2; ++j)
    aq[j] = *(const short8v*)(Qp + (size_t)(qrow0 + q) * DD + j * 32 + g * 8);

  float mrun[4], lrun[4];
  f32x4 oacc[4] = {};
#pragma unroll
  for (int r2 = 0; r2 < 4; ++r2) { mrun[r2] = -1e30f; lrun[r2] = 0.f; }

  char* Pw = (char*)Plds + w * 2048;
  const int kvend = qt * 64;
  for (int kv0 = 0; kv0 <= kvend; kv0 += 64) {
    f32x4 st[4];
#pragma unroll
    for (int c = 0; c < 4; ++c) {
      const u16* kp = Kp + (size_t)(kv0 + c * 16 + q) * DD + g * 8;
      short8v bk0 = *(const short8v*)kp;
      short8v bk1 = *(const short8v*)(kp + 32);
      f32x4 z = {};
      z = mfma_bf16(aq[0], bk0, z);
      z = mfma_bf16(aq[1], bk1, z);
      st[c] = z;
    }
    if (kv0 == kvend) {           // diagonal tile: causal mask
#pragma unroll
      for (int c = 0; c < 4; ++c) {
        int col = kv0 + c * 16 + q;
#pragma unroll
        for (int r2 = 0; r2 < 4; ++r2) {
          int row = qrow0 + g * 4 + r2;
          if (col > row) st[c][r2] = -1e30f;
        }
      }
    }
    float alpha[4];
#pragma unroll
    for (int r2 = 0; r2 < 4; ++r2) {
      float mx = fmaxf(fmaxf(st[0][r2], st[1][r2]), fmaxf(st[2][r2], st[3][r2]));
      mx = fmaxf(mx, __shfl_xor(mx, 1));
      mx = fmaxf(mx, __shfl_xor(mx, 2));
      mx = fmaxf(mx, __shfl_xor(mx, 4));
      mx = fmaxf(mx, __shfl_xor(mx, 8));
      float mnew = fmaxf(mrun[r2], mx);
      alpha[r2] = exp2f((mrun[r2] - mnew) * 1.44269504f);
      mrun[r2] = mnew;
      float s = 0.f;
#pragma unroll
      for (int c = 0; c < 4; ++c) {
        float pv = exp2f((st[c][r2] - mnew) * 1.44269504f);
        st[c][r2] = pv;
        s += pv;
      }
      s += __shfl_xor(s, 1); s += __shfl_xor(s, 2);
      s += __shfl_xor(s, 4); s += __shfl_xor(s, 8);
      lrun[r2] = lrun[r2] * alpha[r2] + s;
#pragma unroll
      for (int t = 0; t < 4; ++t) oacc[t][r2] *= alpha[r2];
    }
    // P -> LDS (bf16, XOR-swizzled to break stride-128B bank conflict)
#pragma unroll
    for (int c = 0; c < 4; ++c) {
      int colb = (c * 16 + q) * 2;
#pragma unroll
      for (int r2 = 0; r2 < 4; ++r2) {
        int row = g * 4 + r2;
        *(u16*)(Pw + row * 128 + (colb ^ ((row & 7) << 4))) = f2b(st[c][r2]);
      }
    }
    asm volatile("s_waitcnt lgkmcnt(0)" ::: "memory");
    short8v pa[2];
#pragma unroll
    for (int j = 0; j < 2; ++j) {
      int colb = (j * 32 + g * 8) * 2;
      pa[j] = *(const short8v*)(Pw + q * 128 + (colb ^ ((q & 7) << 4)));
    }
#pragma unroll
    for (int t = 0; t < 4; ++t) {
      const u16* vp = Vp + (size_t)(t * 16 + q) * SS + kv0 + g * 8;
      short8v bv0 = *(const short8v*)vp;
      short8v bv1 = *(const short8v*)(vp + 32);
      oacc[t] = mfma_bf16(pa[0], bv0, oacc[t]);
      oacc[t] = mfma_bf16(pa[1], bv1, oacc[t]);
    }
  }
  int b = bh >> 4, h = bh & 15;
#pragma unroll
  for (int r2 = 0; r2 < 4; ++r2) {
    float inv = 1.0f / lrun[r2];
    int row = qrow0 + g * 4 + r2;
    size_t base = ((size_t)b * SS + row) * EE + (size_t)h * 64;
#pragma unroll
    for (int t = 0; t < 4; ++t)
      O[base + t * 16 + q] = f2b(oacc[t][r2] * inv);
  }
}

// ---------------- output projection GEMM: out[4096,1024] = O @ Wout + bout (f32) ----------------
__global__ void __launch_bounds__(256) gemm_out_kernel(
    const u16* __restrict__ A, const u16* __restrict__ BT,
    const float* __restrict__ bias, float* __restrict__ Cout) {
  __shared__ u16 As[4096];
  __shared__ u16 Bs[4096];
  const int K = EE;
  int tid = threadIdx.x;
  int w = tid >> 6, lane = tid & 63;
  int g = lane >> 4, q = lane & 15;
  int m0 = blockIdx.y * 128, n0 = blockIdx.x * 128;
  int wm = (w >> 1) * 64, wn = (w & 1) * 64;

  f32x4 acc[4][4] = {};

  int r = tid >> 2;
  int kc = (tid & 3) * 8;
  const u16* ga = A + (size_t)(m0 + r) * K + kc;
  const u16* gb = BT + (size_t)(n0 + r) * K + kc;
  u16* lA0 = As + w * 512;
  u16* lA1 = As + 2048 + w * 512;
  u16* lB0 = Bs + w * 512;
  u16* lB1 = Bs + 2048 + w * 512;

  for (int k0 = 0; k0 < K; k0 += 32) {
    gload_lds16(ga, lA0);
    gload_lds16(ga + 64 * K, lA1);
    gload_lds16(gb, lB0);
    gload_lds16(gb + 64 * K, lB1);
    ga += 32; gb += 32;
    __syncthreads();
    short8v af[4], bfv[4];
#pragma unroll
    for (int m = 0; m < 4; ++m)
      af[m] = *(const short8v*)(As + (wm + m * 16 + q) * 32 + g * 8);
#pragma unroll
    for (int n = 0; n < 4; ++n)
      bfv[n] = *(const short8v*)(Bs + (wn + n * 16 + q) * 32 + g * 8);
#pragma unroll
    for (int m = 0; m < 4; ++m)
#pragma unroll
      for (int n = 0; n < 4; ++n)
        acc[m][n] = mfma_bf16(af[m], bfv[n], acc[m][n]);
    __syncthreads();
  }

#pragma unroll
  for (int m = 0; m < 4; ++m) {
    int row0 = m0 + wm + m * 16 + g * 4;
#pragma unroll
    for (int n = 0; n < 4; ++n) {
      int col = n0 + wn + n * 16 + q;
      float bi = bias[col];
#pragma unroll
      for (int r2 = 0; r2 < 4; ++r2) {
        int row = row0 + r2;
        Cout[(size_t)row * EE + col] = acc[m][n][r2] + bi;
      }
    }
  }
}

extern "C" void kernel_launch(void* const* d_in, const int* in_sizes, int n_in,
                              void* d_out, int out_size, void* d_ws, size_t ws_size,
                              hipStream_t stream) {
  (void)in_sizes; (void)n_in; (void)out_size; (void)ws_size;
  const float* x    = (const float*)d_in[0];
  const float* Wqkv = (const float*)d_in[1];
  const float* bqkv = (const float*)d_in[2];
  const float* Wout = (const float*)d_in[3];
  const float* bout = (const float*)d_in[4];
  float* out = (float*)d_out;

  char* p = (char*)d_ws;
  u16* xb  = (u16*)p; p += (size_t)MT * EE * 2;          // 8 MB
  u16* wqT = (u16*)p; p += (size_t)NQ * EE * 2;          // 6 MB
  u16* woT = (u16*)p; p += (size_t)EE * EE * 2;          // 2 MB
  u16* Qs  = (u16*)p; p += (size_t)BB * HH * SS * DD * 2; // 8 MB
  u16* Ks  = (u16*)p; p += (size_t)BB * HH * SS * DD * 2; // 8 MB
  u16* Vt  = (u16*)p; p += (size_t)BB * HH * DD * SS * 2; // 8 MB
  u16* Ob  = (u16*)p; p += (size_t)MT * EE * 2;           // 8 MB

  cast_kernel<<<dim3((MT * EE / 4) / 256), dim3(256), 0, stream>>>(x, xb, MT * EE);
  transpose_kernel<<<dim3(NQ, EE / 256), dim3(256), 0, stream>>>(Wqkv, wqT, EE, NQ);
  transpose_kernel<<<dim3(EE, EE / 256), dim3(256), 0, stream>>>(Wout, woT, EE, EE);
  gemm_qkv_kernel<<<dim3(NQ / 128, MT / 128), dim3(256), 0, stream>>>(xb, wqT, bqkv, Qs, Ks, Vt);
  attn_kernel<<<dim3(SS / 64, BB * HH), dim3(256), 0, stream>>>(Qs, Ks, Vt, Ob);
  gemm_out_kernel<<<dim3(EE / 128, MT / 128), dim3(256), 0, stream>>>(Ob, woT, bout, out);
}

// Round 2
// 185.341 us; speedup vs baseline: 1.7447x; 1.7447x over previous
//
#include <hip/hip_runtime.h>
#include <hip/hip_bf16.h>

#define BB 2
#define SS 2048
#define EE 1024
#define HH 16
#define DD 64
#define MT (BB*SS)     // 4096 tokens
#define NQ (3*EE)      // 3072

typedef unsigned short u16;
typedef __bf16 bf16t;
typedef bf16t bf16x8 __attribute__((ext_vector_type(8)));
typedef short short8v __attribute__((ext_vector_type(8)));
typedef float f32x4 __attribute__((ext_vector_type(4)));

#define AS1 __attribute__((address_space(1)))
#define AS3 __attribute__((address_space(3)))

__device__ __forceinline__ u16 f2b(float f) {
  unsigned u = __builtin_bit_cast(unsigned, f);
  u += 0x7FFF + ((u >> 16) & 1);   // RNE
  return (u16)(u >> 16);
}

__device__ __forceinline__ void gload_lds16(const void* g, void* l) {
  __builtin_amdgcn_global_load_lds((const AS1 void*)(g), (AS3 void*)(l), 16, 0, 0);
}

__device__ __forceinline__ f32x4 mfma_bf16(short8v a, short8v b, f32x4 c) {
  return __builtin_amdgcn_mfma_f32_16x16x32_bf16(
      __builtin_bit_cast(bf16x8, a), __builtin_bit_cast(bf16x8, b), c, 0, 0, 0);
}

// ---------------- prologue: cast x -> bf16 ----------------
__global__ void __launch_bounds__(256) cast_kernel(const float* __restrict__ in,
                                                   u16* __restrict__ out, int n) {
  int i = (blockIdx.x * 256 + threadIdx.x) * 4;
  if (i + 3 < n) {
    float4 v = *(const float4*)(in + i);
    ushort4 o;
    o.x = f2b(v.x); o.y = f2b(v.y); o.z = f2b(v.z); o.w = f2b(v.w);
    *(ushort4*)(out + i) = o;
  }
}

// W [K][N] f32 -> WT [N][K] bf16, 64x64 LDS tile (coalesced both sides)
__global__ void __launch_bounds__(256) transpose_kernel(const float* __restrict__ W,
                                                        u16* __restrict__ WT,
                                                        int K, int N) {
  __shared__ float t[64][65];
  int k0 = blockIdx.y * 64, n0 = blockIdx.x * 64;
  int r = threadIdx.x >> 4;          // 0..15
  int c4 = (threadIdx.x & 15) * 4;   // 0..60
#pragma unroll
  for (int i = 0; i < 4; ++i) {
    float4 v = *(const float4*)(W + (size_t)(k0 + r + i * 16) * N + n0 + c4);
    t[r + i * 16][c4 + 0] = v.x; t[r + i * 16][c4 + 1] = v.y;
    t[r + i * 16][c4 + 2] = v.z; t[r + i * 16][c4 + 3] = v.w;
  }
  __syncthreads();
#pragma unroll
  for (int i = 0; i < 4; ++i) {
    ushort4 o;
    o.x = f2b(t[c4 + 0][r + i * 16]); o.y = f2b(t[c4 + 1][r + i * 16]);
    o.z = f2b(t[c4 + 2][r + i * 16]); o.w = f2b(t[c4 + 3][r + i * 16]);
    *(ushort4*)(WT + (size_t)(n0 + r + i * 16) * K + k0 + c4) = o;
  }
}

// ---------------- QKV GEMM: C[4096,3072] = x @ Wqkv + b, scatter to Q,K,Vt ----------------
__global__ void __launch_bounds__(256) gemm_qkv_kernel(
    const u16* __restrict__ A, const u16* __restrict__ BT,
    const float* __restrict__ bias,
    u16* __restrict__ Qs, u16* __restrict__ Ks, u16* __restrict__ Vt) {
  __shared__ u16 As[4096];
  __shared__ u16 Bs[4096];
  const int K = EE;
  int tid = threadIdx.x;
  int w = tid >> 6, lane = tid & 63;
  int g = lane >> 4, q = lane & 15;
  int m0 = blockIdx.y * 128, n0 = blockIdx.x * 128;
  int wm = (w >> 1) * 64, wn = (w & 1) * 64;

  f32x4 acc[4][4] = {};

  int r = tid >> 2;
  int kc = (tid & 3) * 8;
  const u16* ga = A + (size_t)(m0 + r) * K + kc;
  const u16* gb = BT + (size_t)(n0 + r) * K + kc;
  u16* lA0 = As + w * 512;
  u16* lA1 = As + 2048 + w * 512;
  u16* lB0 = Bs + w * 512;
  u16* lB1 = Bs + 2048 + w * 512;

  for (int k0 = 0; k0 < K; k0 += 32) {
    gload_lds16(ga, lA0);
    gload_lds16(ga + 64 * K, lA1);
    gload_lds16(gb, lB0);
    gload_lds16(gb + 64 * K, lB1);
    ga += 32; gb += 32;
    __syncthreads();
    short8v af[4], bfv[4];
#pragma unroll
    for (int m = 0; m < 4; ++m)
      af[m] = *(const short8v*)(As + (wm + m * 16 + q) * 32 + g * 8);
#pragma unroll
    for (int n = 0; n < 4; ++n)
      bfv[n] = *(const short8v*)(Bs + (wn + n * 16 + q) * 32 + g * 8);
#pragma unroll
    for (int m = 0; m < 4; ++m)
#pragma unroll
      for (int n = 0; n < 4; ++n)
        acc[m][n] = mfma_bf16(af[m], bfv[n], acc[m][n]);
    __syncthreads();
  }

#pragma unroll
  for (int m = 0; m < 4; ++m) {
    int row0 = m0 + wm + m * 16 + g * 4;
#pragma unroll
    for (int n = 0; n < 4; ++n) {
      int col = n0 + wn + n * 16 + q;
      float bi = bias[col];
      int t = col >> 10;
      int h = (col >> 6) & 15;
      int d = col & 63;
#pragma unroll
      for (int r2 = 0; r2 < 4; ++r2) {
        int row = row0 + r2;
        int b = row >> 11, s = row & 2047;
        float v = acc[m][n][r2] + bi;
        size_t bh = (size_t)b * HH + h;
        if (t == 0)      Qs[(bh * SS + s) * DD + d] = f2b(v * 0.125f);
        else if (t == 1) Ks[(bh * SS + s) * DD + d] = f2b(v);
        else             Vt[(bh * DD + d) * SS + s] = f2b(v);
      }
    }
  }
}

// ---------------- causal flash attention ----------------
// 8 waves x 16 q-rows = 128 q-rows per block; KV tile 64, double-buffered LDS,
// XOR-swizzled (rule 21: linear gload_lds dest + inverse-swizzled global src).
__global__ void __launch_bounds__(512) attn_kernel(
    const u16* __restrict__ Qg, const u16* __restrict__ Kg,
    const u16* __restrict__ Vg, u16* __restrict__ O) {
  __shared__ char lds[49152];   // K0 8K | K1 8K | V0 8K | V1 8K | P 8x2K
  int tid = threadIdx.x;
  int w = tid >> 6, lane = tid & 63;
  int g = lane >> 4, q = lane & 15;
  char* Pw = lds + 32768 + w * 2048;   // per-wave 16x64 bf16, swizzled
  int bh = blockIdx.y;
  int vq = blockIdx.x;
  int qt = (vq & 1) ? (15 - (vq >> 1)) : (vq >> 1);   // big/small pairing
  int q0 = qt * 128;
  int qw = q0 + w * 16;                // wave's first q row
  const char* Qp = (const char*)Qg + (size_t)bh * (SS * 128);
  const char* Kp = (const char*)Kg + (size_t)bh * (SS * 128);
  const char* Vp = (const char*)Vg + (size_t)bh * (SS * 128);  // [d][s] layout

  // Q fragment: A[row=q][k], rows qw+q
  short8v aq[2];
#pragma unroll
  for (int j = 0; j < 2; ++j)
    aq[j] = *(const short8v*)(Qp + (size_t)(qw + q) * 128 + j * 64 + g * 16);

  f32x4 oacc[4] = {};
  float mrun[4], lrun[4];
#pragma unroll
  for (int r2 = 0; r2 < 4; ++r2) { mrun[r2] = -1e30f; lrun[r2] = 0.f; }

  // staging: 512 threads x 16B = one 8KB tile per call pair
  int sr = tid >> 3;                 // row 0..63
  int sc = (tid & 7) * 16;           // 16B chunk within 128B row
  int ssw = sc ^ ((sr & 7) << 4);    // inverse-swizzled source column
  const int nt = 2 * qt + 2;

  {
    gload_lds16(Kp + (size_t)sr * 128 + ssw, lds + w * 1024);                 // K tile 0
    gload_lds16(Vp + (size_t)sr * (SS * 2) + ssw, lds + 16384 + w * 1024);    // V tile 0
  }
  __syncthreads();

  for (int t = 0; t < nt; ++t) {
    int kv0 = t * 64;
    const char* Kc = lds + (t & 1) * 8192;
    const char* Vc = lds + 16384 + (t & 1) * 8192;
    if (t + 1 < nt) {   // issue next-tile staging before compute (2-phase)
      char* kd = lds + ((t + 1) & 1) * 8192;
      char* vd = lds + 16384 + ((t + 1) & 1) * 8192;
      gload_lds16(Kp + (size_t)(kv0 + 64 + sr) * 128 + ssw, kd + w * 1024);
      gload_lds16(Vp + (size_t)sr * (SS * 2) + (kv0 + 64) * 2 + ssw, vd + w * 1024);
    }
    if (kv0 <= qw + 15) {            // wave has unmasked work in this tile
      // ---- QK^T ----
      f32x4 st[4];
#pragma unroll
      for (int c = 0; c < 4; ++c) {
        int row = c * 16 + q;
        const char* kb = Kc + row * 128;
        int sw = (row & 7) << 4;
        short8v b0 = *(const short8v*)(kb + ((g * 16) ^ sw));
        short8v b1 = *(const short8v*)(kb + ((64 + g * 16) ^ sw));
        f32x4 z = {};
        z = mfma_bf16(aq[0], b0, z);
        z = mfma_bf16(aq[1], b1, z);
        st[c] = z;
      }
      if (kv0 + 63 > qw) {           // diagonal tile: causal mask
#pragma unroll
        for (int c = 0; c < 4; ++c) {
          int col = kv0 + c * 16 + q;
#pragma unroll
          for (int r2 = 0; r2 < 4; ++r2) {
            int row = qw + g * 4 + r2;
            if (col > row) st[c][r2] = -1e30f;
          }
        }
      }
      // ---- online softmax (rows split: 4 rows per g-group, reduce over q lanes) ----
#pragma unroll
      for (int r2 = 0; r2 < 4; ++r2) {
        float mx = fmaxf(fmaxf(st[0][r2], st[1][r2]), fmaxf(st[2][r2], st[3][r2]));
        mx = fmaxf(mx, __shfl_xor(mx, 1));
        mx = fmaxf(mx, __shfl_xor(mx, 2));
        mx = fmaxf(mx, __shfl_xor(mx, 4));
        mx = fmaxf(mx, __shfl_xor(mx, 8));
        float mnew = fmaxf(mrun[r2], mx);
        float alpha = exp2f((mrun[r2] - mnew) * 1.44269504f);
        mrun[r2] = mnew;
        float s = 0.f;
#pragma unroll
        for (int c = 0; c < 4; ++c) {
          float pv = exp2f((st[c][r2] - mnew) * 1.44269504f);
          st[c][r2] = pv;
          s += pv;
        }
        s += __shfl_xor(s, 1); s += __shfl_xor(s, 2);
        s += __shfl_xor(s, 4); s += __shfl_xor(s, 8);
        lrun[r2] = lrun[r2] * alpha + s;
#pragma unroll
        for (int vf = 0; vf < 4; ++vf) oacc[vf][r2] *= alpha;
      }
      // ---- P -> per-wave LDS (swizzled), re-fragment for PV ----
#pragma unroll
      for (int c = 0; c < 4; ++c) {
        int colb = (c * 16 + q) * 2;
#pragma unroll
        for (int r2 = 0; r2 < 4; ++r2) {
          int row = g * 4 + r2;
          *(u16*)(Pw + row * 128 + (colb ^ ((row & 7) << 4))) = f2b(st[c][r2]);
        }
      }
      short8v pa[2];
#pragma unroll
      for (int j = 0; j < 2; ++j)
        pa[j] = *(const short8v*)(Pw + q * 128 + (((j * 64 + g * 16)) ^ ((q & 7) << 4)));
      // ---- PV ----
#pragma unroll
      for (int vf = 0; vf < 4; ++vf) {
        int row = vf * 16 + q;
        const char* vb = Vc + row * 128;
        int sw = (row & 7) << 4;
        short8v v0 = *(const short8v*)(vb + ((g * 16) ^ sw));
        short8v v1 = *(const short8v*)(vb + ((64 + g * 16) ^ sw));
        oacc[vf] = mfma_bf16(pa[0], v0, oacc[vf]);
        oacc[vf] = mfma_bf16(pa[1], v1, oacc[vf]);
      }
    }
    __syncthreads();   // drains staged loads; buffer swap safe
  }

  int b = bh >> 4, h = bh & 15;
#pragma unroll
  for (int r2 = 0; r2 < 4; ++r2) {
    float inv = 1.0f / lrun[r2];
    int row = qw + g * 4 + r2;
    u16* base = O + ((size_t)b * SS + row) * EE + h * 64;
#pragma unroll
    for (int vf = 0; vf < 4; ++vf)
      base[vf * 16 + q] = f2b(oacc[vf][r2] * inv);
  }
}

// ---------------- output projection GEMM: out[4096,1024] = O @ Wout + bout (f32) ----------------
__global__ void __launch_bounds__(256) gemm_out_kernel(
    const u16* __restrict__ A, const u16* __restrict__ BT,
    const float* __restrict__ bias, float* __restrict__ Cout) {
  __shared__ u16 As[4096];
  __shared__ u16 Bs[4096];
  const int K = EE;
  int tid = threadIdx.x;
  int w = tid >> 6, lane = tid & 63;
  int g = lane >> 4, q = lane & 15;
  int m0 = blockIdx.y * 128, n0 = blockIdx.x * 128;
  int wm = (w >> 1) * 64, wn = (w & 1) * 64;

  f32x4 acc[4][4] = {};

  int r = tid >> 2;
  int kc = (tid & 3) * 8;
  const u16* ga = A + (size_t)(m0 + r) * K + kc;
  const u16* gb = BT + (size_t)(n0 + r) * K + kc;
  u16* lA0 = As + w * 512;
  u16* lA1 = As + 2048 + w * 512;
  u16* lB0 = Bs + w * 512;
  u16* lB1 = Bs + 2048 + w * 512;

  for (int k0 = 0; k0 < K; k0 += 32) {
    gload_lds16(ga, lA0);
    gload_lds16(ga + 64 * K, lA1);
    gload_lds16(gb, lB0);
    gload_lds16(gb + 64 * K, lB1);
    ga += 32; gb += 32;
    __syncthreads();
    short8v af[4], bfv[4];
#pragma unroll
    for (int m = 0; m < 4; ++m)
      af[m] = *(const short8v*)(As + (wm + m * 16 + q) * 32 + g * 8);
#pragma unroll
    for (int n = 0; n < 4; ++n)
      bfv[n] = *(const short8v*)(Bs + (wn + n * 16 + q) * 32 + g * 8);
#pragma unroll
    for (int m = 0; m < 4; ++m)
#pragma unroll
      for (int n = 0; n < 4; ++n)
        acc[m][n] = mfma_bf16(af[m], bfv[n], acc[m][n]);
    __syncthreads();
  }

#pragma unroll
  for (int m = 0; m < 4; ++m) {
    int row0 = m0 + wm + m * 16 + g * 4;
#pragma unroll
    for (int n = 0; n < 4; ++n) {
      int col = n0 + wn + n * 16 + q;
      float bi = bias[col];
#pragma unroll
      for (int r2 = 0; r2 < 4; ++r2) {
        int row = row0 + r2;
        Cout[(size_t)row * EE + col] = acc[m][n][r2] + bi;
      }
    }
  }
}

extern "C" void kernel_launch(void* const* d_in, const int* in_sizes, int n_in,
                              void* d_out, int out_size, void* d_ws, size_t ws_size,
                              hipStream_t stream) {
  (void)in_sizes; (void)n_in; (void)out_size; (void)ws_size;
  const float* x    = (const float*)d_in[0];
  const float* Wqkv = (const float*)d_in[1];
  const float* bqkv = (const float*)d_in[2];
  const float* Wout = (const float*)d_in[3];
  const float* bout = (const float*)d_in[4];
  float* out = (float*)d_out;

  char* p = (char*)d_ws;
  u16* xb  = (u16*)p; p += (size_t)MT * EE * 2;           // 8 MB
  u16* wqT = (u16*)p; p += (size_t)NQ * EE * 2;           // 6 MB
  u16* woT = (u16*)p; p += (size_t)EE * EE * 2;           // 2 MB
  u16* Qs  = (u16*)p; p += (size_t)BB * HH * SS * DD * 2; // 8 MB
  u16* Ks  = (u16*)p; p += (size_t)BB * HH * SS * DD * 2; // 8 MB
  u16* Vt  = (u16*)p; p += (size_t)BB * HH * DD * SS * 2; // 8 MB
  u16* Ob  = (u16*)p; p += (size_t)MT * EE * 2;           // 8 MB

  cast_kernel<<<dim3((MT * EE / 4) / 256), dim3(256), 0, stream>>>(x, xb, MT * EE);
  transpose_kernel<<<dim3(NQ / 64, EE / 64), dim3(256), 0, stream>>>(Wqkv, wqT, EE, NQ);
  transpose_kernel<<<dim3(EE / 64, EE / 64), dim3(256), 0, stream>>>(Wout, woT, EE, EE);
  gemm_qkv_kernel<<<dim3(NQ / 128, MT / 128), dim3(256), 0, stream>>>(xb, wqT, bqkv, Qs, Ks, Vt);
  attn_kernel<<<dim3(SS / 128, BB * HH), dim3(512), 0, stream>>>(Qs, Ks, Vt, Ob);
  gemm_out_kernel<<<dim3(EE / 128, MT / 128), dim3(256), 0, stream>>>(Ob, woT, bout, out);
}